// Round 1
// baseline (2506.805 us; speedup 1.0000x reference)
//
#include <hip/hip_runtime.h>
#include <math.h>

#define WAYS 5
#define NQN 4096
#define CCH 64
#define TT 25
#define EMBD 26
#define NBATCH (NQN*WAYS)

// workspace float offsets
#define WS_SC 0         // 5*25*64 spt centered [w][i][c]
#define WS_RS 8000      // 125 inv l2 norms
#define WS_SP 8125      // 125 proj
#define WS_QM 8250      // 102400 qry per-token channel mean [q][j]
#define WS_QR 110650    // 102400 qry inv l2 norm
#define WS_TP 213050    // 102400 qry proj

// weight LDS offsets
#define O_QKVW 0
#define O_QKVB 2028
#define O_ATTW 2106
#define O_ATTB 2782
#define O_FC1W 2808
#define O_FC1B 5512
#define O_FC2B 5616
#define O_DECW 5642
#define O_DECB 6292
#define O_L1G 6317
#define O_L1B 6343
#define O_L2G 6369
#define O_L2B 6395
#define WTOT 6421

__global__ void prep_spt(const float* __restrict__ spt, const float* __restrict__ proj_w,
                         const float* __restrict__ proj_b, float* __restrict__ ws) {
    int tid = threadIdx.x;
    if (tid >= 125) return;
    int w = tid / 25, i = tid % 25;
    const float* base = spt + w * 1600 + i;   // stride 25 over channel
    float s = 0.f;
    for (int c = 0; c < 64; c++) s += base[c * 25];
    float m = s * (1.f / 64.f);
    float ss = 0.f, pj = 0.f;
    for (int c = 0; c < 64; c++) {
        float v = base[c * 25] - m;
        ss += v * v; pj += v * proj_w[c];
        ws[WS_SC + (w * 25 + i) * 64 + c] = v;
    }
    ws[WS_RS + w * 25 + i] = rsqrtf(ss + 1e-6f);
    ws[WS_SP + w * 25 + i] = pj + proj_b[0];
}

__global__ void prep_qry(const float* __restrict__ qry, const float* __restrict__ proj_w,
                         const float* __restrict__ proj_b, float* __restrict__ ws) {
    int idx = blockIdx.x * 256 + threadIdx.x;
    if (idx >= NQN * 25) return;
    int q = idx / 25, j = idx % 25;
    const float* base = qry + q * 1600 + j;
    float s = 0.f;
    for (int c = 0; c < 64; c++) s += base[c * 25];
    float m = s * (1.f / 64.f);
    float ss = 0.f, pj = 0.f;
    for (int c = 0; c < 64; c++) {
        float v = base[c * 25] - m;
        ss += v * v; pj += v * proj_w[c];
    }
    ws[WS_QM + idx] = m;
    ws[WS_QR + idx] = rsqrtf(ss + 1e-6f);
    ws[WS_TP + idx] = pj + proj_b[0];
}

// O[m*SO+n] {=|+=} act( scale*sum_k A[m*SA+k]*W[n*WN+k*WK] + bias[n] )
template<int M, int N, int K, int TM, int TN, int SA, int WN, int WK, int SO, bool ADD, bool GELU>
__device__ __forceinline__ void mm(const float* __restrict__ A, const float* __restrict__ W,
                                   const float* __restrict__ bias, float* __restrict__ O,
                                   float scale, int tid) {
    constexpr int GM = M / TM;
    constexpr int GN = (N + TN - 1) / TN;
    for (int v = tid; v < GM * GN; v += 256) {
        const int m0 = (v / GN) * TM, n0 = (v % GN) * TN;
        float acc[TM][TN];
#pragma unroll
        for (int a = 0; a < TM; a++)
#pragma unroll
            for (int c = 0; c < TN; c++) acc[a][c] = 0.f;
#pragma unroll 4
        for (int k = 0; k < K; k++) {
            float av[TM], wv[TN];
#pragma unroll
            for (int a = 0; a < TM; a++) av[a] = A[(m0 + a) * SA + k];
#pragma unroll
            for (int c = 0; c < TN; c++) {
                int nn = n0 + c; if (nn > N - 1) nn = N - 1;
                wv[c] = W[nn * WN + k * WK];
            }
#pragma unroll
            for (int a = 0; a < TM; a++)
#pragma unroll
                for (int c = 0; c < TN; c++) acc[a][c] += av[a] * wv[c];
        }
#pragma unroll
        for (int a = 0; a < TM; a++)
#pragma unroll
            for (int c = 0; c < TN; c++) {
                int n = n0 + c;
                if (n < N) {
                    float r = acc[a][c] * scale + (bias ? bias[n] : 0.f);
                    if (GELU) r = 0.5f * r * (1.f + erff(r * 0.70710678118654752f));
                    if (ADD) O[(m0 + a) * SO + n] += r; else O[(m0 + a) * SO + n] = r;
                }
            }
    }
}

__device__ __forceinline__ void ln_row(const float* __restrict__ x, float* __restrict__ h,
                                       const float* __restrict__ g, const float* __restrict__ bb) {
    float s = 0.f;
#pragma unroll
    for (int e = 0; e < EMBD; e++) s += x[e];
    float m = s * (1.f / EMBD);
    float vv = 0.f;
#pragma unroll
    for (int e = 0; e < EMBD; e++) { float d = x[e] - m; vv += d * d; }
    float r = rsqrtf(vv * (1.f / EMBD) + 1e-6f);
#pragma unroll
    for (int e = 0; e < EMBD; e++) h[e] = (x[e] - m) * r * g[e] + bb[e];
}

__device__ __forceinline__ void xblock(float* __restrict__ xm, float* __restrict__ hm,
                                       float* __restrict__ scr, float* __restrict__ ym,
                                       const float* __restrict__ wlds,
                                       const float* __restrict__ fc2_w, int tid) {
    if (tid < 25) ln_row(xm + tid * 26, hm + tid * 26, wlds + O_L1G, wlds + O_L1B);
    __syncthreads();
    // qkv: (25x26)x(26x78)
    mm<25, 78, 26, 5, 2, 26, 26, 1, 78, false, false>(hm, wlds + O_QKVW, wlds + O_QKVB, scr, 1.f, tid);
    __syncthreads();
    const float SC = 0.27735009811261457f;  // 13^-0.5
    for (int h = 0; h < 2; h++) {
        // scores: q(i)·k(j), K=13
        mm<25, 25, 13, 5, 1, 78, 78, 1, 25, false, false>(scr + h * 13, scr + 26 + h * 13, nullptr, ym, SC, tid);
        __syncthreads();
        if (tid < 25) {  // softmax over keys
            float* row = ym + tid * 25;
            float mx = row[0];
            for (int j = 1; j < 25; j++) mx = fmaxf(mx, row[j]);
            float s = 0.f;
            for (int j = 0; j < 25; j++) { float e = __expf(row[j] - mx); row[j] = e; s += e; }
            float inv = 1.f / s;
            for (int j = 0; j < 25; j++) row[j] *= inv;
        }
        __syncthreads();
        // o = P @ v  -> oatt at scr+1950, row stride 26
        mm<25, 13, 25, 5, 1, 25, 1, 78, 26, false, false>(ym, scr + 52 + h * 13, nullptr, scr + 1950 + h * 13, 1.f, tid);
        __syncthreads();
    }
    // attn proj + residual
    mm<25, 26, 26, 5, 2, 26, 26, 1, 26, true, false>(scr + 1950, wlds + O_ATTW, wlds + O_ATTB, xm, 1.f, tid);
    __syncthreads();
    if (tid < 25) ln_row(xm + tid * 26, hm + tid * 26, wlds + O_L2G, wlds + O_L2B);
    __syncthreads();
    // fc1 + gelu -> scr[0:2600]
    mm<25, 104, 26, 5, 4, 26, 26, 1, 104, false, true>(hm, wlds + O_FC1W, wlds + O_FC1B, scr, 1.f, tid);
    __syncthreads();
    // fc2 + residual (weights from global/L2)
    mm<25, 26, 104, 5, 2, 104, 104, 1, 26, true, false>(scr, fc2_w, wlds + O_FC2B, xm, 1.f, tid);
    __syncthreads();
}

__global__ void __launch_bounds__(256)
fused_kernel(const float* __restrict__ qry, const float* __restrict__ ws,
             const float* __restrict__ pos_x, const float* __restrict__ pos_y,
             const float* __restrict__ qkv_w, const float* __restrict__ qkv_b,
             const float* __restrict__ attn_w, const float* __restrict__ attn_b,
             const float* __restrict__ ln1_g, const float* __restrict__ ln1_b,
             const float* __restrict__ ln2_g, const float* __restrict__ ln2_b,
             const float* __restrict__ fc1_w, const float* __restrict__ fc1_b,
             const float* __restrict__ fc2_w, const float* __restrict__ fc2_b,
             const float* __restrict__ dec_w, const float* __restrict__ dec_b,
             float* __restrict__ out) {
    __shared__ __align__(16) float sc[25 * 64];   // spt l2-normalized, [i][c]
    __shared__ __align__(16) float tcb[25 * 64];  // qry l2-normalized, [j][c]
    __shared__ float rsv[25], rtv[25], spv[25], tpv[25];
    __shared__ __align__(16) float corrm[625];
    __shared__ __align__(16) float xm[650];
    __shared__ __align__(16) float hm[650];
    __shared__ __align__(16) float scr[2600];     // qkv 0..1950 | oatt 1950..2600 ; later mlp-hid 0..2600
    __shared__ __align__(16) float ym[640];       // attn probs / dec out / refined / final red
    __shared__ float asv[25], aqv[25];
    __shared__ __align__(16) float wlds[WTOT];

    const int b = blockIdx.x, q = b / WAYS, w = b % WAYS, tid = threadIdx.x;

    // stage weights into LDS (fc2_w stays in L2)
    for (int i = tid; i < 2028; i += 256) wlds[O_QKVW + i] = qkv_w[i];
    for (int i = tid; i < 78; i += 256)   wlds[O_QKVB + i] = qkv_b[i];
    for (int i = tid; i < 676; i += 256)  wlds[O_ATTW + i] = attn_w[i];
    if (tid < 26) wlds[O_ATTB + tid] = attn_b[tid];
    for (int i = tid; i < 2704; i += 256) wlds[O_FC1W + i] = fc1_w[i];
    if (tid < 104) wlds[O_FC1B + tid] = fc1_b[tid];
    if (tid < 26) wlds[O_FC2B + tid] = fc2_b[tid];
    for (int i = tid; i < 650; i += 256)  wlds[O_DECW + i] = dec_w[i];
    if (tid < 25) wlds[O_DECB + tid] = dec_b[tid];
    if (tid < 26) {
        wlds[O_L1G + tid] = ln1_g[tid]; wlds[O_L1B + tid] = ln1_b[tid];
        wlds[O_L2G + tid] = ln2_g[tid]; wlds[O_L2B + tid] = ln2_b[tid];
    }
    // spt features (normalized)
    for (int e = tid; e < 1600; e += 256)
        sc[e] = ws[WS_SC + w * 1600 + e] * ws[WS_RS + w * 25 + (e >> 6)];
    if (tid < 25) {
        rsv[tid] = ws[WS_RS + w * 25 + tid];
        spv[tid] = ws[WS_SP + w * 25 + tid];
        rtv[tid] = ws[WS_QR + q * 25 + tid];
        tpv[tid] = ws[WS_TP + q * 25 + tid];
    }
    // qry features (centered+normalized), transposed into [j][c]
    for (int e = tid; e < 1600; e += 256) {
        int c = e / 25, j = e % 25;
        tcb[j * 64 + c] = (qry[q * 1600 + e] - ws[WS_QM + q * 25 + j]) * ws[WS_QR + q * 25 + j];
    }
    __syncthreads();

    // corr[i][j] = s_i · t_j
    mm<25, 25, 64, 5, 1, 64, 64, 1, 25, false, false>(sc, tcb, nullptr, corrm, 1.f, tid);
    __syncthreads();

    // x1: rows = qry tokens; [corr^T | tp] + pos
    for (int e = tid; e < 650; e += 256) {
        int t = e / 26, d = e % 26;
        float p = (d < 13) ? pos_x[(t % 5) * 13 + d] : pos_y[(t / 5) * 13 + (d - 13)];
        float base = (d < 25) ? corrm[d * 25 + t] : tpv[t];
        xm[e] = base + p;
    }
    __syncthreads();

    xblock(xm, hm, scr, ym, wlds, fc2_w, tid);

    // dec1 -> ym[t][m]
    mm<25, 25, 26, 5, 1, 26, 26, 1, 25, false, false>(xm, wlds + O_DECW, wlds + O_DECB, ym, 1.f, tid);
    __syncthreads();

    // x2: rows = spt tokens; [dec1^T + corr | sp] + pos
    for (int e = tid; e < 650; e += 256) {
        int t = e / 26, d = e % 26;
        float p = (d < 13) ? pos_x[(t % 5) * 13 + d] : pos_y[(t / 5) * 13 + (d - 13)];
        float base = (d < 25) ? (ym[d * 25 + t] + corrm[t * 25 + d]) : spv[t];
        xm[e] = base + p;
    }
    __syncthreads();

    xblock(xm, hm, scr, ym, wlds, fc2_w, tid);

    // dec2 + corr -> refined in ym
    mm<25, 25, 26, 5, 1, 26, 26, 1, 25, false, false>(xm, wlds + O_DECW, wlds + O_DECB, ym, 1.f, tid);
    __syncthreads();
    for (int e = tid; e < 625; e += 256) ym[e] += corrm[e];
    __syncthreads();

    // attn_s: per column j, gnorm+softmax over i; P -> corrm
    if (tid < 25) {
        int j = tid;
        float s = 0.f;
        for (int i = 0; i < 25; i++) s += ym[i * 25 + j];
        float m = s * 0.04f;
        float ss = 0.f;
        for (int i = 0; i < 25; i++) { float d = ym[i * 25 + j] - m; ss += d * d; }
        float rinv = rsqrtf(ss * (1.f / 24.f) + 1e-5f) * 0.2f;   // /T_ATTN
        float mx = -1e30f;
        for (int i = 0; i < 25; i++) { float z = (ym[i * 25 + j] - m) * rinv; corrm[i * 25 + j] = z; mx = fmaxf(mx, z); }
        float se = 0.f;
        for (int i = 0; i < 25; i++) { float e2 = __expf(corrm[i * 25 + j] - mx); corrm[i * 25 + j] = e2; se += e2; }
        float inv = 1.f / se;
        for (int i = 0; i < 25; i++) corrm[i * 25 + j] *= inv;
    }
    __syncthreads();
    if (tid < 25) {  // row sums, fold 1/25 and recover centered scale (/rs)
        int i = tid; float s = 0.f;
        for (int j = 0; j < 25; j++) s += corrm[i * 25 + j];
        asv[i] = s * 0.04f / rsv[i];
    }
    __syncthreads();
    // attn_q: per row i, gnorm+softmax over j; Q -> corrm
    if (tid < 25) {
        int i = tid;
        float s = 0.f;
        for (int j = 0; j < 25; j++) s += ym[i * 25 + j];
        float m = s * 0.04f;
        float ss = 0.f;
        for (int j = 0; j < 25; j++) { float d = ym[i * 25 + j] - m; ss += d * d; }
        float rinv = rsqrtf(ss * (1.f / 24.f) + 1e-5f) * 0.2f;
        float mx = -1e30f;
        for (int j = 0; j < 25; j++) { float z = (ym[i * 25 + j] - m) * rinv; corrm[i * 25 + j] = z; mx = fmaxf(mx, z); }
        float se = 0.f;
        for (int j = 0; j < 25; j++) { float e2 = __expf(corrm[i * 25 + j] - mx); corrm[i * 25 + j] = e2; se += e2; }
        float inv = 1.f / se;
        for (int j = 0; j < 25; j++) corrm[i * 25 + j] *= inv;
    }
    __syncthreads();
    if (tid < 25) {
        int j = tid; float s = 0.f;
        for (int i = 0; i < 25; i++) s += corrm[i * 25 + j];
        aqv[j] = s * 0.04f / rtv[j];
    }
    __syncthreads();

    // pooled features per channel (ym reused as red buffer)
    if (tid < 64) {
        float s = 0.f;
        for (int i = 0; i < 25; i++) s += asv[i] * sc[i * 64 + tid];
        ym[tid] = s;
        float s2 = 0.f;
        for (int j = 0; j < 25; j++) s2 += aqv[j] * tcb[j * 64 + tid];
        ym[64 + tid] = s2;
    }
    __syncthreads();
    if (tid == 0) {
        float d = 0.f, n1 = 0.f, n2 = 0.f;
        for (int c = 0; c < 64; c++) {
            float a = ym[c], bb2 = ym[64 + c];
            d += a * bb2; n1 += a * a; n2 += bb2 * bb2;
        }
        n1 = fmaxf(sqrtf(n1), 1e-8f);
        n2 = fmaxf(sqrtf(n2), 1e-8f);
        out[b] = d / (n1 * n2) * 5.f;   // /TEMP (0.2)
    }
}

extern "C" void kernel_launch(void* const* d_in, const int* in_sizes, int n_in,
                              void* d_out, int out_size, void* d_ws, size_t ws_size,
                              hipStream_t stream) {
    const float* spt    = (const float*)d_in[0];
    const float* qry    = (const float*)d_in[1];
    const float* proj_w = (const float*)d_in[2];
    const float* proj_b = (const float*)d_in[3];
    const float* pos_x  = (const float*)d_in[4];
    const float* pos_y  = (const float*)d_in[5];
    const float* ln1_g  = (const float*)d_in[6];
    const float* ln1_b  = (const float*)d_in[7];
    const float* qkv_w  = (const float*)d_in[8];
    const float* qkv_b  = (const float*)d_in[9];
    const float* attn_w = (const float*)d_in[10];
    const float* attn_b = (const float*)d_in[11];
    const float* ln2_g  = (const float*)d_in[12];
    const float* ln2_b  = (const float*)d_in[13];
    const float* fc1_w  = (const float*)d_in[14];
    const float* fc1_b  = (const float*)d_in[15];
    const float* fc2_w  = (const float*)d_in[16];
    const float* fc2_b  = (const float*)d_in[17];
    const float* dec_w  = (const float*)d_in[18];
    const float* dec_b  = (const float*)d_in[19];
    float* ws  = (float*)d_ws;
    float* out = (float*)d_out;

    prep_spt<<<1, 128, 0, stream>>>(spt, proj_w, proj_b, ws);
    prep_qry<<<(NQN * 25 + 255) / 256, 256, 0, stream>>>(qry, proj_w, proj_b, ws);
    fused_kernel<<<NBATCH, 256, 0, stream>>>(qry, ws, pos_x, pos_y, qkv_w, qkv_b, attn_w, attn_b,
                                             ln1_g, ln1_b, ln2_g, ln2_b, fc1_w, fc1_b,
                                             fc2_w, fc2_b, dec_w, dec_b, out);
}

// Round 2
// 1278.958 us; speedup vs baseline: 1.9600x; 1.9600x over previous
//
#include <hip/hip_runtime.h>
#include <math.h>

#define WAYS 5
#define NQN 4096
#define NBATCH (NQN*WAYS)
#define SAB 68   // padded stride for sc/tcb (16B aligned, 4-bank shift/row)

// workspace float offsets
#define WS_SC 0         // 5*25*64 spt centered [w][i][c]
#define WS_RS 8000      // 125 inv l2 norms
#define WS_SP 8125      // 125 proj
#define WS_QM 8250      // 102400 qry per-token channel mean [q][j]
#define WS_QR 110650    // 102400 qry inv l2 norm
#define WS_TP 213050    // 102400 qry proj

// cpar offsets (small params staged in LDS)
#define P_L1G 0
#define P_L1B 26
#define P_L2G 52
#define P_L2B 78
#define P_QKVB 104
#define P_ATTB 182
#define P_FC1B 208
#define P_FC2B 312
#define P_DECB 338
#define P_TOT 363

__global__ void prep_spt(const float* __restrict__ spt, const float* __restrict__ proj_w,
                         const float* __restrict__ proj_b, float* __restrict__ ws) {
    int tid = threadIdx.x;
    if (tid >= 125) return;
    int w = tid / 25, i = tid % 25;
    const float* base = spt + w * 1600 + i;
    float s = 0.f;
    for (int c = 0; c < 64; c++) s += base[c * 25];
    float m = s * (1.f / 64.f);
    float ss = 0.f, pj = 0.f;
    for (int c = 0; c < 64; c++) {
        float v = base[c * 25] - m;
        ss += v * v; pj += v * proj_w[c];
        ws[WS_SC + (w * 25 + i) * 64 + c] = v;
    }
    ws[WS_RS + w * 25 + i] = rsqrtf(ss + 1e-6f);
    ws[WS_SP + w * 25 + i] = pj + proj_b[0];
}

__global__ void prep_qry(const float* __restrict__ qry, const float* __restrict__ proj_w,
                         const float* __restrict__ proj_b, float* __restrict__ ws) {
    int idx = blockIdx.x * 256 + threadIdx.x;
    if (idx >= NQN * 25) return;
    int q = idx / 25, j = idx % 25;
    const float* base = qry + q * 1600 + j;
    float s = 0.f;
    for (int c = 0; c < 64; c++) s += base[c * 25];
    float m = s * (1.f / 64.f);
    float ss = 0.f, pj = 0.f;
    for (int c = 0; c < 64; c++) {
        float v = base[c * 25] - m;
        ss += v * v; pj += v * proj_w[c];
    }
    ws[WS_QM + idx] = m;
    ws[WS_QR + idx] = rsqrtf(ss + 1e-6f);
    ws[WS_TP + idx] = pj + proj_b[0];
}

// O[m*SO+n] {=|+=} act( scale*sum_k A[m*SA+k]*W[n*WN+k*WK] + bias[n] )
// VW>1 requires WK==1, K%VW==0, SA%VW==0, WN%VW==0 (and 4B*VW alignment).
template<int M, int N, int K, int TM, int TN, int SA, int WN, int WK, int SO, int VW,
         bool ADD, bool GELU>
__device__ __forceinline__ void mm(const float* __restrict__ A, const float* __restrict__ W,
                                   const float* __restrict__ bias, float* __restrict__ O,
                                   float scale, int tid) {
    static_assert(M % TM == 0 && N % TN == 0, "tile");
    static_assert(VW == 1 || (WK == 1 && K % VW == 0 && SA % VW == 0 && WN % VW == 0), "vec");
    constexpr int GM = M / TM, GN = N / TN;
    for (int v = tid; v < GM * GN; v += 256) {
        const int m0 = (v / GN) * TM, n0 = (v % GN) * TN;
        float acc[TM][TN];
#pragma unroll
        for (int a = 0; a < TM; a++)
#pragma unroll
            for (int c = 0; c < TN; c++) acc[a][c] = 0.f;

        if constexpr (VW == 4) {
#pragma unroll
            for (int k = 0; k < K; k += 4) {
                float4 av[TM], wv[TN];
#pragma unroll
                for (int a = 0; a < TM; a++) av[a] = *(const float4*)(A + (m0 + a) * SA + k);
#pragma unroll
                for (int c = 0; c < TN; c++) wv[c] = *(const float4*)(W + (n0 + c) * WN + k);
#pragma unroll
                for (int a = 0; a < TM; a++)
#pragma unroll
                    for (int c = 0; c < TN; c++) {
                        acc[a][c] += av[a].x * wv[c].x;
                        acc[a][c] += av[a].y * wv[c].y;
                        acc[a][c] += av[a].z * wv[c].z;
                        acc[a][c] += av[a].w * wv[c].w;
                    }
            }
        } else if constexpr (VW == 2) {
#pragma unroll 4
            for (int k = 0; k < K; k += 2) {
                float2 av[TM], wv[TN];
#pragma unroll
                for (int a = 0; a < TM; a++) av[a] = *(const float2*)(A + (m0 + a) * SA + k);
#pragma unroll
                for (int c = 0; c < TN; c++) wv[c] = *(const float2*)(W + (n0 + c) * WN + k);
#pragma unroll
                for (int a = 0; a < TM; a++)
#pragma unroll
                    for (int c = 0; c < TN; c++) {
                        acc[a][c] += av[a].x * wv[c].x;
                        acc[a][c] += av[a].y * wv[c].y;
                    }
            }
        } else {
#pragma unroll 4
            for (int k = 0; k < K; k++) {
                float av[TM], wv[TN];
#pragma unroll
                for (int a = 0; a < TM; a++) av[a] = A[(m0 + a) * SA + k];
#pragma unroll
                for (int c = 0; c < TN; c++) wv[c] = W[(n0 + c) * WN + k * WK];
#pragma unroll
                for (int a = 0; a < TM; a++)
#pragma unroll
                    for (int c = 0; c < TN; c++) acc[a][c] += av[a] * wv[c];
            }
        }
#pragma unroll
        for (int a = 0; a < TM; a++)
#pragma unroll
            for (int c = 0; c < TN; c++) {
                int n = n0 + c;
                float r = acc[a][c] * scale + (bias ? bias[n] : 0.f);
                if (GELU) r = 0.5f * r * (1.f + erff(r * 0.70710678118654752f));
                if (ADD) O[(m0 + a) * SO + n] += r; else O[(m0 + a) * SO + n] = r;
            }
    }
}

__device__ __forceinline__ void ln_row(const float* __restrict__ x, float* __restrict__ h,
                                       const float* __restrict__ g, const float* __restrict__ bb) {
    float s = 0.f;
#pragma unroll
    for (int e = 0; e < 26; e++) s += x[e];
    float m = s * (1.f / 26.f);
    float vv = 0.f;
#pragma unroll
    for (int e = 0; e < 26; e++) { float d = x[e] - m; vv += d * d; }
    float r = rsqrtf(vv * (1.f / 26.f) + 1e-6f);
#pragma unroll
    for (int e = 0; e < 26; e++) h[e] = (x[e] - m) * r * g[e] + bb[e];
}

__device__ __forceinline__ void xblock(float* __restrict__ xm, float* __restrict__ hm,
                                       float* __restrict__ scr, float* __restrict__ ym,
                                       const float* __restrict__ cpar,
                                       const float* __restrict__ qkv_w,
                                       const float* __restrict__ attn_w,
                                       const float* __restrict__ fc1_w,
                                       const float* __restrict__ fc2_w, int tid) {
    if (tid < 25) ln_row(xm + tid * 26, hm + tid * 26, cpar + P_L1G, cpar + P_L1B);
    __syncthreads();
    // qkv: (25x26)x(26x78), weights from global/L2
    mm<25, 78, 26, 5, 3, 26, 26, 1, 78, 2, false, false>(hm, qkv_w, cpar + P_QKVB, scr, 1.f, tid);
    __syncthreads();
    // scores, both heads batched: 250 items
    {
        const float SC = 0.27735009811261457f;  // 13^-0.5
        for (int v = tid; v < 250; v += 256) {
            int h = v / 125, r = v % 125;
            int m0 = (r / 25) * 5, j = r % 25;
            const float* kb = scr + j * 78 + 26 + h * 13;
            float acc[5] = {0.f, 0.f, 0.f, 0.f, 0.f};
#pragma unroll
            for (int k = 0; k < 13; k++) {
                float kv = kb[k];
#pragma unroll
                for (int a = 0; a < 5; a++) acc[a] += scr[(m0 + a) * 78 + h * 13 + k] * kv;
            }
            float* orow = ym + h * 625;
#pragma unroll
            for (int a = 0; a < 5; a++) orow[(m0 + a) * 25 + j] = acc[a] * SC;
        }
    }
    __syncthreads();
    if (tid < 50) {  // softmax over keys, 2 heads x 25 rows
        float* row = ym + (tid / 25) * 625 + (tid % 25) * 25;
        float mx = row[0];
        for (int j = 1; j < 25; j++) mx = fmaxf(mx, row[j]);
        float s = 0.f;
        for (int j = 0; j < 25; j++) { float e = __expf(row[j] - mx); row[j] = e; s += e; }
        float inv = 1.f / s;
        for (int j = 0; j < 25; j++) row[j] *= inv;
    }
    __syncthreads();
    // o = P @ V, both heads: 130 items -> oatt at scr+1950 (stride 26)
    for (int v = tid; v < 130; v += 256) {
        int h = v / 65, r = v % 65;
        int m0 = (r / 13) * 5, n = r % 13;
        const float* P = ym + h * 625;
        float acc[5] = {0.f, 0.f, 0.f, 0.f, 0.f};
#pragma unroll
        for (int k = 0; k < 25; k++) {
            float vv = scr[k * 78 + 52 + h * 13 + n];
#pragma unroll
            for (int a = 0; a < 5; a++) acc[a] += P[(m0 + a) * 25 + k] * vv;
        }
#pragma unroll
        for (int a = 0; a < 5; a++) scr[1950 + (m0 + a) * 26 + h * 13 + n] = acc[a];
    }
    __syncthreads();
    // attn proj + residual
    mm<25, 26, 26, 5, 2, 26, 26, 1, 26, 2, true, false>(scr + 1950, attn_w, cpar + P_ATTB, xm, 1.f, tid);
    __syncthreads();
    if (tid < 25) ln_row(xm + tid * 26, hm + tid * 26, cpar + P_L2G, cpar + P_L2B);
    __syncthreads();
    // fc1 + gelu -> scr[0:2600]
    mm<25, 104, 26, 5, 4, 26, 26, 1, 104, 2, false, true>(hm, fc1_w, cpar + P_FC1B, scr, 1.f, tid);
    __syncthreads();
    // fc2 + residual
    mm<25, 26, 104, 5, 2, 104, 104, 1, 26, 2, true, false>(scr, fc2_w, cpar + P_FC2B, xm, 1.f, tid);
    __syncthreads();
}

__global__ void __launch_bounds__(256, 4)
fused_kernel(const float* __restrict__ qry, const float* __restrict__ ws,
             const float* __restrict__ pos_x, const float* __restrict__ pos_y,
             const float* __restrict__ qkv_w, const float* __restrict__ qkv_b,
             const float* __restrict__ attn_w, const float* __restrict__ attn_b,
             const float* __restrict__ ln1_g, const float* __restrict__ ln1_b,
             const float* __restrict__ ln2_g, const float* __restrict__ ln2_b,
             const float* __restrict__ fc1_w, const float* __restrict__ fc1_b,
             const float* __restrict__ fc2_w, const float* __restrict__ fc2_b,
             const float* __restrict__ dec_w, const float* __restrict__ dec_b,
             float* __restrict__ out) {
    __shared__ __align__(16) float sc[25 * SAB];   // spt l2-normalized [i][c], stride 68
    __shared__ __align__(16) float tcb[25 * SAB];  // qry l2-normalized [j][c], stride 68
    __shared__ float rsv[25], rtv[25], spv[25], tpv[25];
    __shared__ __align__(16) float corrm[625];
    __shared__ __align__(16) float xm[650];
    __shared__ __align__(16) float hm[650];
    __shared__ __align__(16) float scr[2600];      // qkv 0..1950 | oatt 1950..2600 ; later mlp-hid
    __shared__ __align__(16) float ym[1250];       // 2-head scores / dec out / refined / final red
    __shared__ float asv[25], aqv[25];
    __shared__ __align__(16) float cpar[P_TOT];

    const int b = blockIdx.x, q = b / WAYS, w = b % WAYS, tid = threadIdx.x;

    // stage small params
    if (tid < 26) {
        cpar[P_L1G + tid] = ln1_g[tid]; cpar[P_L1B + tid] = ln1_b[tid];
        cpar[P_L2G + tid] = ln2_g[tid]; cpar[P_L2B + tid] = ln2_b[tid];
        cpar[P_ATTB + tid] = attn_b[tid]; cpar[P_FC2B + tid] = fc2_b[tid];
    }
    if (tid < 78) cpar[P_QKVB + tid] = qkv_b[tid];
    if (tid < 104) cpar[P_FC1B + tid] = fc1_b[tid];
    if (tid < 25) cpar[P_DECB + tid] = dec_b[tid];

    // spt features (normalized), stride 68
    for (int e = tid; e < 1600; e += 256) {
        int i = e >> 6, c = e & 63;
        sc[i * SAB + c] = ws[WS_SC + w * 1600 + e] * ws[WS_RS + w * 25 + i];
    }
    if (tid < 25) {
        rsv[tid] = ws[WS_RS + w * 25 + tid];
        spv[tid] = ws[WS_SP + w * 25 + tid];
        rtv[tid] = ws[WS_QR + q * 25 + tid];
        tpv[tid] = ws[WS_TP + q * 25 + tid];
    }
    // qry features (centered+normalized), transposed into [j][c], stride 68
    for (int e = tid; e < 1600; e += 256) {
        int c = e / 25, j = e % 25;
        tcb[j * SAB + c] = (qry[q * 1600 + e] - ws[WS_QM + q * 25 + j]) * ws[WS_QR + q * 25 + j];
    }
    __syncthreads();

    // corr[i][j] = s_i · t_j  (K=64, float4, padded strides)
    mm<25, 25, 64, 5, 1, SAB, SAB, 1, 25, 4, false, false>(sc, tcb, nullptr, corrm, 1.f, tid);
    __syncthreads();

    // x1: rows = qry tokens; [corr^T | tp] + pos
    for (int e = tid; e < 650; e += 256) {
        int t = e / 26, d = e % 26;
        float p = (d < 13) ? pos_x[(t % 5) * 13 + d] : pos_y[(t / 5) * 13 + (d - 13)];
        float base = (d < 25) ? corrm[d * 25 + t] : tpv[t];
        xm[e] = base + p;
    }
    __syncthreads();

    xblock(xm, hm, scr, ym, cpar, qkv_w, attn_w, fc1_w, fc2_w, tid);

    // dec1 -> ym[t][m]
    mm<25, 25, 26, 5, 1, 26, 26, 1, 25, 2, false, false>(xm, dec_w, cpar + P_DECB, ym, 1.f, tid);
    __syncthreads();

    // x2: rows = spt tokens; [dec1^T + corr | sp] + pos
    for (int e = tid; e < 650; e += 256) {
        int t = e / 26, d = e % 26;
        float p = (d < 13) ? pos_x[(t % 5) * 13 + d] : pos_y[(t / 5) * 13 + (d - 13)];
        float base = (d < 25) ? (ym[d * 25 + t] + corrm[t * 25 + d]) : spv[t];
        xm[e] = base + p;
    }
    __syncthreads();

    xblock(xm, hm, scr, ym, cpar, qkv_w, attn_w, fc1_w, fc2_w, tid);

    // dec2 + corr -> refined in ym
    mm<25, 25, 26, 5, 1, 26, 26, 1, 25, 2, false, false>(xm, dec_w, cpar + P_DECB, ym, 1.f, tid);
    __syncthreads();
    for (int e = tid; e < 625; e += 256) ym[e] += corrm[e];
    __syncthreads();

    // attn_s: per column j, gnorm+softmax over i; P -> corrm
    if (tid < 25) {
        int j = tid;
        float s = 0.f;
        for (int i = 0; i < 25; i++) s += ym[i * 25 + j];
        float m = s * 0.04f;
        float ss = 0.f;
        for (int i = 0; i < 25; i++) { float d = ym[i * 25 + j] - m; ss += d * d; }
        float rinv = rsqrtf(ss * (1.f / 24.f) + 1e-5f) * 0.2f;   // /T_ATTN
        float mx = -1e30f;
        for (int i = 0; i < 25; i++) { float z = (ym[i * 25 + j] - m) * rinv; corrm[i * 25 + j] = z; mx = fmaxf(mx, z); }
        float se = 0.f;
        for (int i = 0; i < 25; i++) { float e2 = __expf(corrm[i * 25 + j] - mx); corrm[i * 25 + j] = e2; se += e2; }
        float inv = 1.f / se;
        for (int i = 0; i < 25; i++) corrm[i * 25 + j] *= inv;
    }
    __syncthreads();
    if (tid < 25) {
        int i = tid; float s = 0.f;
        for (int j = 0; j < 25; j++) s += corrm[i * 25 + j];
        asv[i] = s * 0.04f / rsv[i];
    }
    __syncthreads();
    // attn_q: per row i, gnorm+softmax over j; Q -> corrm
    if (tid < 25) {
        int i = tid;
        float s = 0.f;
        for (int j = 0; j < 25; j++) s += ym[i * 25 + j];
        float m = s * 0.04f;
        float ss = 0.f;
        for (int j = 0; j < 25; j++) { float d = ym[i * 25 + j] - m; ss += d * d; }
        float rinv = rsqrtf(ss * (1.f / 24.f) + 1e-5f) * 0.2f;
        float mx = -1e30f;
        for (int j = 0; j < 25; j++) { float z = (ym[i * 25 + j] - m) * rinv; corrm[i * 25 + j] = z; mx = fmaxf(mx, z); }
        float se = 0.f;
        for (int j = 0; j < 25; j++) { float e2 = __expf(corrm[i * 25 + j] - mx); corrm[i * 25 + j] = e2; se += e2; }
        float inv = 1.f / se;
        for (int j = 0; j < 25; j++) corrm[i * 25 + j] *= inv;
    }
    __syncthreads();
    if (tid < 25) {
        int j = tid; float s = 0.f;
        for (int i = 0; i < 25; i++) s += corrm[i * 25 + j];
        aqv[j] = s * 0.04f / rtv[j];
    }
    __syncthreads();

    // pooled features per channel
    if (tid < 64) {
        float s = 0.f;
        for (int i = 0; i < 25; i++) s += asv[i] * sc[i * SAB + tid];
        ym[tid] = s;
        float s2 = 0.f;
        for (int j = 0; j < 25; j++) s2 += aqv[j] * tcb[j * SAB + tid];
        ym[64 + tid] = s2;
    }
    __syncthreads();
    if (tid == 0) {
        float d = 0.f, n1 = 0.f, n2 = 0.f;
        for (int c = 0; c < 64; c++) {
            float a = ym[c], bb2 = ym[64 + c];
            d += a * bb2; n1 += a * a; n2 += bb2 * bb2;
        }
        n1 = fmaxf(sqrtf(n1), 1e-8f);
        n2 = fmaxf(sqrtf(n2), 1e-8f);
        out[b] = d / (n1 * n2) * 5.f;   // /TEMP
    }
}

extern "C" void kernel_launch(void* const* d_in, const int* in_sizes, int n_in,
                              void* d_out, int out_size, void* d_ws, size_t ws_size,
                              hipStream_t stream) {
    const float* spt    = (const float*)d_in[0];
    const float* qry    = (const float*)d_in[1];
    const float* proj_w = (const float*)d_in[2];
    const float* proj_b = (const float*)d_in[3];
    const float* pos_x  = (const float*)d_in[4];
    const float* pos_y  = (const float*)d_in[5];
    const float* ln1_g  = (const float*)d_in[6];
    const float* ln1_b  = (const float*)d_in[7];
    const float* qkv_w  = (const float*)d_in[8];
    const float* qkv_b  = (const float*)d_in[9];
    const float* attn_w = (const float*)d_in[10];
    const float* attn_b = (const float*)d_in[11];
    const float* ln2_g  = (const float*)d_in[12];
    const float* ln2_b  = (const float*)d_in[13];
    const float* fc1_w  = (const float*)d_in[14];
    const float* fc1_b  = (const float*)d_in[15];
    const float* fc2_w  = (const float*)d_in[16];
    const float* fc2_b  = (const float*)d_in[17];
    const float* dec_w  = (const float*)d_in[18];
    const float* dec_b  = (const float*)d_in[19];
    float* ws  = (float*)d_ws;
    float* out = (float*)d_out;

    prep_spt<<<1, 128, 0, stream>>>(spt, proj_w, proj_b, ws);
    prep_qry<<<(NQN * 25 + 255) / 256, 256, 0, stream>>>(qry, proj_w, proj_b, ws);
    fused_kernel<<<NBATCH, 256, 0, stream>>>(qry, ws, pos_x, pos_y, qkv_w, qkv_b, attn_w, attn_b,
                                             ln1_g, ln1_b, ln2_g, ln2_b, fc1_w, fc1_b,
                                             fc2_w, fc2_b, dec_w, dec_b, out);
}